// Round 7
// baseline (1456.176 us; speedup 1.0000x reference)
//
#include <hip/hip_runtime.h>
#include <hip/hip_bf16.h>
#include <hip/hip_fp16.h>

#define N_NODES 20000
#define N_EDGES 640000
#define N_HIDDEN 128
#define EDGE_DIM 8
#define NODE_DIM 16
#define N_BLOCKS 15
#define N_BINARY 10

typedef __attribute__((ext_vector_type(8))) _Float16 f16x8;
typedef __attribute__((ext_vector_type(4))) float f32x4;
typedef unsigned int uint;
typedef unsigned short ushort;

union U2H {
  uint u;
  __half2 h;
};
static __device__ __forceinline__ __half2 u2h2(uint u) {
  U2H c; c.u = u; return c.h;
}
static __device__ __forceinline__ ushort f2h_bits(float f) {
  union { _Float16 h; ushort u; } c;
  c.h = (_Float16)f;
  return c.u;
}

// ---- embed: h = log(x+1) @ embW + embB ; x2p = packed f16(h/std) -----------
__global__ void k_embed(const float* __restrict__ x, const float* __restrict__ eW,
                        const float* __restrict__ ebias, float* __restrict__ h,
                        uint* __restrict__ x2p) {
  int wid = (blockIdx.x * blockDim.x + threadIdx.x) >> 6;
  int lane = threadIdx.x & 63;
  if (wid >= N_NODES) return;
  float xl[NODE_DIM];
#pragma unroll
  for (int k = 0; k < NODE_DIM; k++) xl[k] = logf(x[wid * NODE_DIM + k] + 1.0f);
  int c0 = lane, c1 = lane + 64;
  float h0 = ebias[c0], h1 = ebias[c1];
#pragma unroll
  for (int k = 0; k < NODE_DIM; k++) {
    h0 += xl[k] * eW[k * N_HIDDEN + c0];
    h1 += xl[k] * eW[k * N_HIDDEN + c1];
  }
  float ss = h0 + h1, s2 = h0 * h0 + h1 * h1;
#pragma unroll
  for (int m = 1; m < 64; m <<= 1) {
    ss += __shfl_xor(ss, m);
    s2 += __shfl_xor(s2, m);
  }
  float var = (s2 - ss * ss * (1.0f / 128.0f)) * (1.0f / 127.0f);
  float inv = 1.0f / sqrtf(var);
  size_t o = (size_t)wid * N_HIDDEN;
  h[o + c0] = h0;
  h[o + c1] = h1;
  uint pk = (uint)f2h_bits(h0 * inv) | ((uint)f2h_bits(h1 * inv) << 16);
  x2p[(size_t)wid * 64 + lane] = pk;
}

// ---------------- CSR build: count also records each edge's rank ------------
__global__ void k_count(const int* __restrict__ ei, int* __restrict__ deg,
                        int* __restrict__ rnk) {
  int e = blockIdx.x * blockDim.x + threadIdx.x;
  if (e < N_EDGES) rnk[e] = atomicAdd(&deg[ei[N_EDGES + e]], 1);
}

__global__ __launch_bounds__(1024) void k_scan(const int* __restrict__ deg,
                                               int* __restrict__ off) {
  __shared__ int wsum[16];
  int t = threadIdx.x;
  int lane = t & 63, w = t >> 6;
  int base = t * 20;
  int loc[20];
  int s = 0;
#pragma unroll
  for (int i = 0; i < 20; i++) {
    int idx = base + i;
    int d = (idx < N_NODES) ? deg[idx] : 0;
    loc[i] = s;
    s += d;
  }
  int incl = s;
#pragma unroll
  for (int m = 1; m < 64; m <<= 1) {
    int o = __shfl_up(incl, m);
    if (lane >= m) incl += o;
  }
  if (lane == 63) wsum[w] = incl;
  __syncthreads();
  if (w == 0) {
    int xv = (lane < 16) ? wsum[lane] : 0;
#pragma unroll
    for (int m = 1; m < 16; m <<= 1) {
      int o = __shfl_up(xv, m);
      if (lane >= m) xv += o;
    }
    if (lane < 16) wsum[lane] = xv;
  }
  __syncthreads();
  int woff = (w == 0) ? 0 : wsum[w - 1];
  int texcl = woff + incl - s;
#pragma unroll
  for (int i = 0; i < 20; i++) {
    int idx = base + i;
    if (idx < N_NODES) off[idx] = texcl + loc[i];
  }
  if (t == 0) off[N_NODES] = wsum[15];
}

// permute edges dst-sorted (atomic-free: pos = off[dst] + rnk[e])
__global__ void k_permute(const int* __restrict__ ei, const float* __restrict__ eattr,
                          const int* __restrict__ off, const int* __restrict__ rnk,
                          uint* __restrict__ srcoff, _Float16* __restrict__ ea_h) {
  int e = blockIdx.x * blockDim.x + threadIdx.x;
  if (e >= N_EDGES) return;
  int d = ei[N_EDGES + e];
  int pos = off[d] + rnk[e];
  srcoff[pos] = (uint)ei[e] * 64u;
  const float4* ap = (const float4*)(eattr + (size_t)e * 8);
  float4 a0 = ap[0], a1 = ap[1];
  f16x8 r;
  r[0] = (_Float16)logf(a0.x + 1.0f);
  r[1] = (_Float16)logf(a0.y + 1.0f);
  r[2] = (_Float16)logf(a0.z + 1.0f);
  r[3] = (_Float16)logf(a0.w + 1.0f);
  r[4] = (_Float16)logf(a1.x + 1.0f);
  r[5] = (_Float16)logf(a1.y + 1.0f);
  r[6] = (_Float16)logf(a1.z + 1.0f);
  r[7] = (_Float16)logf(a1.w + 1.0f);
  *(f16x8*)(ea_h + (size_t)pos * 8) = r;
}

// ---- weight transpose+f16. layer 0 gets paired k-order to match z_p --------
__global__ void k_prep_w(const float* __restrict__ W1, const float* __restrict__ W2,
                         const float* __restrict__ W3, _Float16* __restrict__ Wt) {
  __shared__ _Float16 t[128][130];
  int m = blockIdx.x;  // 0..44 = blk*3+layer
  int blk = m / 3, layer = m % 3;
  const float* src = (layer == 0 ? W1 : layer == 1 ? W2 : W3) + (size_t)blk * 16384;
  int tid = threadIdx.x;
  for (int idx = tid; idx < 16384; idx += 256) {
    int k = idx >> 7, n = idx & 127;
    t[k][n] = (_Float16)src[idx];
  }
  __syncthreads();
  _Float16* dst = Wt + (size_t)m * 16384;
  if (layer == 0) {
    for (int idx = tid; idx < 16384; idx += 256) {
      int n = idx >> 7, p = idx & 127;
      int k = (p >> 1) + 64 * (p & 1);  // paired k-order
      dst[idx] = t[k][n];
    }
  } else {
    for (int idx = tid; idx < 16384; idx += 256) {
      int n = idx >> 7, k = idx & 127;
      dst[idx] = t[k][n];
    }
  }
}

// -------- message+aggregate: 2 waves/node + 2-stage software pipeline --------
__global__ __launch_bounds__(256) void k_msg(
    const int* __restrict__ off, const uint* __restrict__ srcoff,
    const _Float16* __restrict__ ea_h, const uint* __restrict__ x2p,
    const float* __restrict__ eW, const float* __restrict__ ebias,
    uint* __restrict__ z_p, uint* __restrict__ zB_p) {
  int gw = (blockIdx.x * blockDim.x + threadIdx.x) >> 6;  // global wave id
  int lane = threadIdx.x & 63;
  if (gw >= 2 * N_NODES) return;
  int node = gw >> 1;
  int half = gw & 1;
  int nodeU = __builtin_amdgcn_readfirstlane(node);

  __half2 w0pk[4], w1pk[4];
#pragma unroll
  for (int j = 0; j < 4; j++) {
    w0pk[j] = __floats2half2_rn(eW[(2 * j) * N_HIDDEN + lane],
                                eW[(2 * j + 1) * N_HIDDEN + lane]);
    w1pk[j] = __floats2half2_rn(eW[(2 * j) * N_HIDDEN + lane + 64],
                                eW[(2 * j + 1) * N_HIDDEN + lane + 64]);
  }
  __half2 bb01 = __floats2half2_rn(ebias[lane], ebias[lane + 64]);

  int beg = off[nodeU], end = off[nodeU + 1];
  int mid = (beg + end) >> 1;
  int eBeg = half ? mid : beg;
  int eEnd = half ? end : mid;

  float acc0 = 0.f, acc1 = 0.f;

#define EDGE_COMPUTE(EV, UA)                                                   \
  {                                                                            \
    __half2 pA = __hmul2(u2h2((EV).x), w0pk[0]);                               \
    pA = __hfma2(u2h2((EV).y), w0pk[1], pA);                                   \
    pA = __hfma2(u2h2((EV).z), w0pk[2], pA);                                   \
    pA = __hfma2(u2h2((EV).w), w0pk[3], pA);                                   \
    __half2 pB = __hmul2(u2h2((EV).x), w1pk[0]);                               \
    pB = __hfma2(u2h2((EV).y), w1pk[1], pB);                                   \
    pB = __hfma2(u2h2((EV).z), w1pk[2], pB);                                   \
    pB = __hfma2(u2h2((EV).w), w1pk[3], pB);                                   \
    __half v0 = __hadd(__low2half(pA), __high2half(pA));                       \
    __half v1 = __hadd(__low2half(pB), __high2half(pB));                       \
    __half2 mm = __hadd2(__halves2half2(v0, v1), __hadd2(u2h2(UA), bb01));     \
    acc0 += fmaxf(__low2float(mm), 0.f);                                       \
    acc1 += fmaxf(__high2float(mm), 0.f);                                      \
  }

#define SLOADG(SO, EV, EE)                                                     \
  {                                                                            \
    int eU_ = __builtin_amdgcn_readfirstlane(EE);                              \
    SO[0] = srcoff[eU_];                                                       \
    SO[1] = srcoff[eU_ + 1];                                                   \
    SO[2] = srcoff[eU_ + 2];                                                   \
    SO[3] = srcoff[eU_ + 3];                                                   \
    const uint4* ep_ = (const uint4*)(ea_h + (size_t)eU_ * 8);                 \
    EV[0] = ep_[0];                                                            \
    EV[1] = ep_[1];                                                            \
    EV[2] = ep_[2];                                                            \
    EV[3] = ep_[3];                                                            \
  }
#define GATHERG(UA, SO)                                                        \
  {                                                                            \
    UA[0] = x2p[SO[0] + lane];                                                 \
    UA[1] = x2p[SO[1] + lane];                                                 \
    UA[2] = x2p[SO[2] + lane];                                                 \
    UA[3] = x2p[SO[3] + lane];                                                 \
  }
#define COMPG(EV, UA)                                                          \
  {                                                                            \
    EDGE_COMPUTE(EV[0], UA[0]);                                                \
    EDGE_COMPUTE(EV[1], UA[1]);                                                \
    EDGE_COMPUTE(EV[2], UA[2]);                                                \
    EDGE_COMPUTE(EV[3], UA[3]);                                                \
  }

  uint soA[4], uaA[4], soB[4], uaB[4];
  uint4 evA[4], evB[4];

  int total = eEnd - eBeg;
  int n4 = total >> 2;
  int e = eBeg;
  if (n4 > 0) {
    SLOADG(soA, evA, e);
    GATHERG(uaA, soA);
    if (n4 > 1) SLOADG(soB, evB, e + 4);
    for (int g = 0; g < n4; ++g, e += 4) {
      if ((g & 1) == 0) {
        if (g + 1 < n4) GATHERG(uaB, soB);
        COMPG(evA, uaA);
        if (g + 2 < n4) SLOADG(soA, evA, e + 8);
      } else {
        if (g + 1 < n4) GATHERG(uaA, soA);
        COMPG(evB, uaB);
        if (g + 2 < n4) SLOADG(soB, evB, e + 8);
      }
    }
  }
  for (; e < eEnd; ++e) {
    int eU = __builtin_amdgcn_readfirstlane(e);
    uint so = srcoff[eU];
    uint4 ev = *(const uint4*)(ea_h + (size_t)eU * 8);
    uint ua = x2p[so + lane];
    EDGE_COMPUTE(ev, ua);
  }
#undef COMPG
#undef GATHERG
#undef SLOADG
#undef EDGE_COMPUTE

  if (half == 0) {
    uint xp = x2p[(size_t)node * 64 + lane];
    float z0 = __low2float(u2h2(xp)) + acc0;
    float z1 = __high2float(u2h2(xp)) + acc1;
    uint pk = (uint)f2h_bits(z0) | ((uint)f2h_bits(z1) << 16);
    z_p[(size_t)node * 64 + lane] = pk;
  } else {
    uint pk = (uint)f2h_bits(acc0) | ((uint)f2h_bits(acc1) << 16);
    zB_p[(size_t)node * 64 + lane] = pk;
  }
}

// -------- MFMA MLP: 32 nodes/block, 4 waves N-split (2 rowgrp x 2 colhalf) --
__global__ __launch_bounds__(256) void k_mlp(
    const uint* __restrict__ z_p, const uint* __restrict__ zB_p,
    const _Float16* __restrict__ Wt, const float* __restrict__ b1,
    const float* __restrict__ b2, const float* __restrict__ b3,
    float* __restrict__ h, uint* __restrict__ x2p) {
  __shared__ __align__(16) _Float16 lz[32][136];
  __shared__ float zf[32][132];
  int tid = threadIdx.x;
  int w = tid >> 6, lane = tid & 63;
  int l15 = lane & 15, g = lane >> 4;
  int wr = w >> 1, wc = w & 1;
  int g0 = blockIdx.x * 32;           // 625 * 32 = 20000 exactly
  int rowL = wr * 16 + l15;           // local A row 0..31
  int nodeA = g0 + rowL;

  f32x4 acc[4];
  f16x8 a[4];

  // ---- layer 1: A = z_p + zB_p (paired k-order; Wt layer0 matches) ----
  const _Float16* zrowA = (const _Float16*)(z_p + (size_t)nodeA * 64);
  const _Float16* zrowB = (const _Float16*)(zB_p + (size_t)nodeA * 64);
#pragma unroll
  for (int kk = 0; kk < 4; kk++) {
    f16x8 za = *(const f16x8*)(zrowA + kk * 32 + g * 8);
    f16x8 zb = *(const f16x8*)(zrowB + kk * 32 + g * 8);
    a[kk] = za + zb;
  }
#pragma unroll
  for (int c = 0; c < 4; c++) {
    float bv = b1[wc * 64 + c * 16 + l15];
    acc[c] = (f32x4){bv, bv, bv, bv};
  }
#pragma unroll
  for (int c = 0; c < 4; c++) {
    int col = wc * 64 + c * 16 + l15;
#pragma unroll
    for (int kk = 0; kk < 4; kk++) {
      f16x8 bf = *(const f16x8*)(Wt + (size_t)col * 128 + kk * 32 + g * 8);
      acc[c] = __builtin_amdgcn_mfma_f32_16x16x32_f16(a[kk], bf, acc[c], 0, 0, 0);
    }
  }
#pragma unroll
  for (int c = 0; c < 4; c++)
#pragma unroll
    for (int r = 0; r < 4; r++)
      lz[wr * 16 + 4 * g + r][wc * 64 + c * 16 + l15] = (_Float16)fmaxf(acc[c][r], 0.f);
  __syncthreads();

  // ---- layer 2 ----
#pragma unroll
  for (int kk = 0; kk < 4; kk++) a[kk] = *(const f16x8*)&lz[rowL][kk * 32 + g * 8];
  __syncthreads();  // all reads of lz done before overwrite
#pragma unroll
  for (int c = 0; c < 4; c++) {
    float bv = b2[wc * 64 + c * 16 + l15];
    acc[c] = (f32x4){bv, bv, bv, bv};
  }
  {
    const _Float16* W2t = Wt + 16384;
#pragma unroll
    for (int c = 0; c < 4; c++) {
      int col = wc * 64 + c * 16 + l15;
#pragma unroll
      for (int kk = 0; kk < 4; kk++) {
        f16x8 bf = *(const f16x8*)(W2t + (size_t)col * 128 + kk * 32 + g * 8);
        acc[c] = __builtin_amdgcn_mfma_f32_16x16x32_f16(a[kk], bf, acc[c], 0, 0, 0);
      }
    }
  }
#pragma unroll
  for (int c = 0; c < 4; c++)
#pragma unroll
    for (int r = 0; r < 4; r++)
      lz[wr * 16 + 4 * g + r][wc * 64 + c * 16 + l15] = (_Float16)fmaxf(acc[c][r], 0.f);
  __syncthreads();

  // ---- layer 3 (no relu) ----
#pragma unroll
  for (int kk = 0; kk < 4; kk++) a[kk] = *(const f16x8*)&lz[rowL][kk * 32 + g * 8];
#pragma unroll
  for (int c = 0; c < 4; c++) {
    float bv = b3[wc * 64 + c * 16 + l15];
    acc[c] = (f32x4){bv, bv, bv, bv};
  }
  {
    const _Float16* W3t = Wt + 32768;
#pragma unroll
    for (int c = 0; c < 4; c++) {
      int col = wc * 64 + c * 16 + l15;
#pragma unroll
      for (int kk = 0; kk < 4; kk++) {
        f16x8 bf = *(const f16x8*)(W3t + (size_t)col * 128 + kk * 32 + g * 8);
        acc[c] = __builtin_amdgcn_mfma_f32_16x16x32_f16(a[kk], bf, acc[c], 0, 0, 0);
      }
    }
  }
  // stage z3 to f32 LDS for cross-wave norm
#pragma unroll
  for (int c = 0; c < 4; c++)
#pragma unroll
    for (int r = 0; r < 4; r++)
      zf[wr * 16 + 4 * g + r][wc * 64 + c * 16 + l15] = acc[c][r];
  __syncthreads();

  // ---- epilogue: per-node y = z3/std; h += y; x2p = packed f16(h/std) ----
  for (int i = 0; i < 8; ++i) {
    int nl = w * 8 + i;
    int n = g0 + nl;
    float z0 = zf[nl][lane], z1 = zf[nl][lane + 64];
    float ss = z0 + z1, s2 = z0 * z0 + z1 * z1;
#pragma unroll
    for (int m = 1; m < 64; m <<= 1) {
      ss += __shfl_xor(ss, m);
      s2 += __shfl_xor(s2, m);
    }
    float inv = 1.0f / sqrtf((s2 - ss * ss * (1.0f / 128.0f)) * (1.0f / 127.0f));
    size_t o = (size_t)n * 128;
    float h0 = h[o + lane] + z0 * inv;
    float h1 = h[o + lane + 64] + z1 * inv;
    float ts = h0 + h1, t2 = h0 * h0 + h1 * h1;
#pragma unroll
    for (int m = 1; m < 64; m <<= 1) {
      ts += __shfl_xor(ts, m);
      t2 += __shfl_xor(t2, m);
    }
    float inv2 = 1.0f / sqrtf((t2 - ts * ts * (1.0f / 128.0f)) * (1.0f / 127.0f));
    h[o + lane] = h0;
    h[o + lane + 64] = h1;
    uint pk = (uint)f2h_bits(h0 * inv2) | ((uint)f2h_bits(h1 * inv2) << 16);
    x2p[(size_t)n * 64 + lane] = pk;
  }
}

// -------- output --------
__global__ void k_out(const float* __restrict__ h, const float* __restrict__ oW,
                      const float* __restrict__ ob, float* __restrict__ out) {
  int wid = (blockIdx.x * blockDim.x + threadIdx.x) >> 6;
  int lane = threadIdx.x & 63;
  if (wid >= N_NODES) return;
  int c0 = lane, c1 = lane + 64;
  float w0 = 0.f, w1 = 0.f, bsum = 0.f;
#pragma unroll
  for (int j = 0; j < N_BINARY; j++) {
    float sc = (float)(1 << j);
    w0 += oW[c0 * N_BINARY + j] * sc;
    w1 += oW[c1 * N_BINARY + j] * sc;
    bsum += ob[j] * sc;
  }
  size_t o = (size_t)wid * 128;
  float v = h[o + c0] * w0 + h[o + c1] * w1;
#pragma unroll
  for (int m = 1; m < 64; m <<= 1) v += __shfl_xor(v, m);
  if (lane == 0) out[wid] = v * (1.0f / sqrtf(15.0f)) + bsum;
}

extern "C" void kernel_launch(void* const* d_in, const int* in_sizes, int n_in,
                              void* d_out, int out_size, void* d_ws, size_t ws_size,
                              hipStream_t stream) {
  const float* x = (const float*)d_in[0];
  const int* ei = (const int*)d_in[1];
  const float* eattr = (const float*)d_in[2];
  const float* embW = (const float*)d_in[3];
  const float* embB = (const float*)d_in[4];
  const float* edgeW = (const float*)d_in[5];
  const float* edgeB = (const float*)d_in[6];
  const float* W1 = (const float*)d_in[7];
  const float* b1 = (const float*)d_in[8];
  const float* W2 = (const float*)d_in[9];
  const float* b2 = (const float*)d_in[10];
  const float* W3 = (const float*)d_in[11];
  const float* b3 = (const float*)d_in[12];
  const float* outW = (const float*)d_in[13];
  const float* outB = (const float*)d_in[14];
  float* out = (float*)d_out;

  char* base = (char*)d_ws;
  size_t o = 0;
  auto carve = [&](size_t bytes) {
    size_t start = o;
    o = (start + bytes + 255) & ~(size_t)255;
    return (void*)(base + start);
  };
  int* deg = (int*)carve(N_NODES * sizeof(int));
  int* off = (int*)carve((N_NODES + 1) * sizeof(int));
  int* rnk = (int*)carve(N_EDGES * sizeof(int));
  uint* srcoff = (uint*)carve(N_EDGES * sizeof(uint));
  _Float16* ea_h = (_Float16*)carve((size_t)N_EDGES * EDGE_DIM * 2);
  uint* x2p = (uint*)carve((size_t)N_NODES * 64 * sizeof(uint));
  uint* z_p = (uint*)carve((size_t)N_NODES * 64 * sizeof(uint));
  uint* zB_p = (uint*)carve((size_t)N_NODES * 64 * sizeof(uint));
  float* h = (float*)carve((size_t)N_NODES * N_HIDDEN * sizeof(float));
  _Float16* Wt = (_Float16*)carve((size_t)45 * 16384 * 2);

  hipMemsetAsync(deg, 0, N_NODES * sizeof(int), stream);
  k_embed<<<N_NODES / 4, 256, 0, stream>>>(x, embW, embB, h, x2p);
  k_count<<<(N_EDGES + 255) / 256, 256, 0, stream>>>(ei, deg, rnk);
  k_scan<<<1, 1024, 0, stream>>>(deg, off);
  k_permute<<<(N_EDGES + 255) / 256, 256, 0, stream>>>(ei, eattr, off, rnk, srcoff, ea_h);
  k_prep_w<<<45, 256, 0, stream>>>(W1, W2, W3, Wt);

  for (int b = 0; b < N_BLOCKS; b++) {
    k_msg<<<(2 * N_NODES) / 4, 256, 0, stream>>>(
        off, srcoff, ea_h, x2p, edgeW + (size_t)b * EDGE_DIM * N_HIDDEN,
        edgeB + (size_t)b * N_HIDDEN, z_p, zB_p);
    k_mlp<<<N_NODES / 32, 256, 0, stream>>>(
        z_p, zB_p, Wt + (size_t)b * 3 * 16384, b1 + (size_t)b * N_HIDDEN,
        b2 + (size_t)b * N_HIDDEN, b3 + (size_t)b * N_HIDDEN, h, x2p);
  }
  k_out<<<N_NODES / 4, 256, 0, stream>>>(h, outW, outB, out);
}

// Round 8
// 957.219 us; speedup vs baseline: 1.5213x; 1.5213x over previous
//
#include <hip/hip_runtime.h>
#include <hip/hip_bf16.h>
#include <hip/hip_fp16.h>

#define N_NODES 20000
#define N_EDGES 640000
#define N_HIDDEN 128
#define EDGE_DIM 8
#define NODE_DIM 16
#define N_BLOCKS 15
#define N_BINARY 10

typedef __attribute__((ext_vector_type(8))) _Float16 f16x8;
typedef __attribute__((ext_vector_type(4))) float f32x4;
typedef unsigned int uint;
typedef unsigned short ushort;

union U2H {
  uint u;
  __half2 h;
};
static __device__ __forceinline__ __half2 u2h2(uint u) {
  U2H c; c.u = u; return c.h;
}
static __device__ __forceinline__ ushort f2h_bits(float f) {
  union { _Float16 h; ushort u; } c;
  c.h = (_Float16)f;
  return c.u;
}

// ---- embed: h = log(x+1) @ embW + embB ; x2p = packed f16(h/std) -----------
__global__ void k_embed(const float* __restrict__ x, const float* __restrict__ eW,
                        const float* __restrict__ ebias, float* __restrict__ h,
                        uint* __restrict__ x2p) {
  int wid = (blockIdx.x * blockDim.x + threadIdx.x) >> 6;
  int lane = threadIdx.x & 63;
  if (wid >= N_NODES) return;
  float xl[NODE_DIM];
#pragma unroll
  for (int k = 0; k < NODE_DIM; k++) xl[k] = logf(x[wid * NODE_DIM + k] + 1.0f);
  int c0 = lane, c1 = lane + 64;
  float h0 = ebias[c0], h1 = ebias[c1];
#pragma unroll
  for (int k = 0; k < NODE_DIM; k++) {
    h0 += xl[k] * eW[k * N_HIDDEN + c0];
    h1 += xl[k] * eW[k * N_HIDDEN + c1];
  }
  float ss = h0 + h1, s2 = h0 * h0 + h1 * h1;
#pragma unroll
  for (int m = 1; m < 64; m <<= 1) {
    ss += __shfl_xor(ss, m);
    s2 += __shfl_xor(s2, m);
  }
  float var = (s2 - ss * ss * (1.0f / 128.0f)) * (1.0f / 127.0f);
  float inv = 1.0f / sqrtf(var);
  size_t o = (size_t)wid * N_HIDDEN;
  h[o + c0] = h0;
  h[o + c1] = h1;
  uint pk = (uint)f2h_bits(h0 * inv) | ((uint)f2h_bits(h1 * inv) << 16);
  x2p[(size_t)wid * 64 + lane] = pk;
}

// ---------------- CSR build: count also records each edge's rank ------------
__global__ void k_count(const int* __restrict__ ei, int* __restrict__ deg,
                        int* __restrict__ rnk) {
  int e = blockIdx.x * blockDim.x + threadIdx.x;
  if (e < N_EDGES) rnk[e] = atomicAdd(&deg[ei[N_EDGES + e]], 1);
}

__global__ __launch_bounds__(1024) void k_scan(const int* __restrict__ deg,
                                               int* __restrict__ off) {
  __shared__ int wsum[16];
  int t = threadIdx.x;
  int lane = t & 63, w = t >> 6;
  int base = t * 20;
  int loc[20];
  int s = 0;
#pragma unroll
  for (int i = 0; i < 20; i++) {
    int idx = base + i;
    int d = (idx < N_NODES) ? deg[idx] : 0;
    loc[i] = s;
    s += d;
  }
  int incl = s;
#pragma unroll
  for (int m = 1; m < 64; m <<= 1) {
    int o = __shfl_up(incl, m);
    if (lane >= m) incl += o;
  }
  if (lane == 63) wsum[w] = incl;
  __syncthreads();
  if (w == 0) {
    int xv = (lane < 16) ? wsum[lane] : 0;
#pragma unroll
    for (int m = 1; m < 16; m <<= 1) {
      int o = __shfl_up(xv, m);
      if (lane >= m) xv += o;
    }
    if (lane < 16) wsum[lane] = xv;
  }
  __syncthreads();
  int woff = (w == 0) ? 0 : wsum[w - 1];
  int texcl = woff + incl - s;
#pragma unroll
  for (int i = 0; i < 20; i++) {
    int idx = base + i;
    if (idx < N_NODES) off[idx] = texcl + loc[i];
  }
  if (t == 0) off[N_NODES] = wsum[15];
}

// permute edges dst-sorted (atomic-free: pos = off[dst] + rnk[e])
__global__ void k_permute(const int* __restrict__ ei, const float* __restrict__ eattr,
                          const int* __restrict__ off, const int* __restrict__ rnk,
                          uint* __restrict__ srcoff, _Float16* __restrict__ ea_h) {
  int e = blockIdx.x * blockDim.x + threadIdx.x;
  if (e >= N_EDGES) return;
  int d = ei[N_EDGES + e];
  int pos = off[d] + rnk[e];
  srcoff[pos] = (uint)ei[e] * 64u;
  const float4* ap = (const float4*)(eattr + (size_t)e * 8);
  float4 a0 = ap[0], a1 = ap[1];
  f16x8 r;
  r[0] = (_Float16)logf(a0.x + 1.0f);
  r[1] = (_Float16)logf(a0.y + 1.0f);
  r[2] = (_Float16)logf(a0.z + 1.0f);
  r[3] = (_Float16)logf(a0.w + 1.0f);
  r[4] = (_Float16)logf(a1.x + 1.0f);
  r[5] = (_Float16)logf(a1.y + 1.0f);
  r[6] = (_Float16)logf(a1.z + 1.0f);
  r[7] = (_Float16)logf(a1.w + 1.0f);
  *(f16x8*)(ea_h + (size_t)pos * 8) = r;
}

// ---- weight transpose+f16. layer 0 gets paired k-order to match packed z ---
__global__ void k_prep_w(const float* __restrict__ W1, const float* __restrict__ W2,
                         const float* __restrict__ W3, _Float16* __restrict__ Wt) {
  __shared__ _Float16 t[128][130];
  int m = blockIdx.x;  // 0..44 = blk*3+layer
  int blk = m / 3, layer = m % 3;
  const float* src = (layer == 0 ? W1 : layer == 1 ? W2 : W3) + (size_t)blk * 16384;
  int tid = threadIdx.x;
  for (int idx = tid; idx < 16384; idx += 256) {
    int k = idx >> 7, n = idx & 127;
    t[k][n] = (_Float16)src[idx];
  }
  __syncthreads();
  _Float16* dst = Wt + (size_t)m * 16384;
  if (layer == 0) {
    for (int idx = tid; idx < 16384; idx += 256) {
      int n = idx >> 7, p = idx & 127;
      int k = (p >> 1) + 64 * (p & 1);  // paired k-order
      dst[idx] = t[k][n];
    }
  } else {
    for (int idx = tid; idx < 16384; idx += 256) {
      int n = idx >> 7, k = idx & 127;
      dst[idx] = t[k][n];
    }
  }
}

// ======== FUSED per-GNN-block kernel: msg + 3-layer MLP + norm ==============
// 1250 blocks x 256 thr; 16 nodes/block; z lives in LDS only.
__global__ __launch_bounds__(256) void k_block(
    const int* __restrict__ off, const uint* __restrict__ srcoff,
    const _Float16* __restrict__ ea_h, const uint* __restrict__ x2in,
    const float* __restrict__ eW, const float* __restrict__ ebias,
    const _Float16* __restrict__ Wt, const float* __restrict__ b1,
    const float* __restrict__ b2, const float* __restrict__ b3,
    float* __restrict__ h, uint* __restrict__ x2out) {
  __shared__ __align__(16) uint lzU[16 * 68];  // rows pitch 68 uints (272B, 16B-aligned)
  __shared__ float zf[16][132];
  int tid = threadIdx.x;
  int w = tid >> 6, lane = tid & 63;
  int l15 = lane & 15, g = lane >> 4;
  int g0 = blockIdx.x * 16;  // 1250*16 = 20000 exact

  // ---------------- phase 1: message + aggregate (wave owns 4 nodes) --------
  __half2 w0pk[4], w1pk[4];
#pragma unroll
  for (int j = 0; j < 4; j++) {
    w0pk[j] = __floats2half2_rn(eW[(2 * j) * N_HIDDEN + lane],
                                eW[(2 * j + 1) * N_HIDDEN + lane]);
    w1pk[j] = __floats2half2_rn(eW[(2 * j) * N_HIDDEN + lane + 64],
                                eW[(2 * j + 1) * N_HIDDEN + lane + 64]);
  }
  __half2 bb01 = __floats2half2_rn(ebias[lane], ebias[lane + 64]);

#define EDGE_COMPUTE(EV, UA)                                                   \
  {                                                                            \
    __half2 pA = __hmul2(u2h2((EV).x), w0pk[0]);                               \
    pA = __hfma2(u2h2((EV).y), w0pk[1], pA);                                   \
    pA = __hfma2(u2h2((EV).z), w0pk[2], pA);                                   \
    pA = __hfma2(u2h2((EV).w), w0pk[3], pA);                                   \
    __half2 pB = __hmul2(u2h2((EV).x), w1pk[0]);                               \
    pB = __hfma2(u2h2((EV).y), w1pk[1], pB);                                   \
    pB = __hfma2(u2h2((EV).z), w1pk[2], pB);                                   \
    pB = __hfma2(u2h2((EV).w), w1pk[3], pB);                                   \
    __half v0 = __hadd(__low2half(pA), __high2half(pA));                       \
    __half v1 = __hadd(__low2half(pB), __high2half(pB));                       \
    __half2 mm = __hadd2(__halves2half2(v0, v1), __hadd2(u2h2(UA), bb01));     \
    acc0 += fmaxf(__low2float(mm), 0.f);                                       \
    acc1 += fmaxf(__high2float(mm), 0.f);                                      \
  }
#define SLOAD4(SO, EV, EE)                                                     \
  {                                                                            \
    int eU_ = __builtin_amdgcn_readfirstlane(EE);                              \
    SO[0] = srcoff[eU_];                                                       \
    SO[1] = srcoff[eU_ + 1];                                                   \
    SO[2] = srcoff[eU_ + 2];                                                   \
    SO[3] = srcoff[eU_ + 3];                                                   \
    const uint4* ep_ = (const uint4*)(ea_h + (size_t)eU_ * 8);                 \
    EV[0] = ep_[0];                                                            \
    EV[1] = ep_[1];                                                            \
    EV[2] = ep_[2];                                                            \
    EV[3] = ep_[3];                                                            \
  }
#define GATHER4(UA, SO)                                                        \
  {                                                                            \
    UA[0] = x2in[SO[0] + lane];                                                \
    UA[1] = x2in[SO[1] + lane];                                                \
    UA[2] = x2in[SO[2] + lane];                                                \
    UA[3] = x2in[SO[3] + lane];                                                \
  }
#define COMP4(EV, UA)                                                          \
  {                                                                            \
    EDGE_COMPUTE(EV[0], UA[0]);                                                \
    EDGE_COMPUTE(EV[1], UA[1]);                                                \
    EDGE_COMPUTE(EV[2], UA[2]);                                                \
    EDGE_COMPUTE(EV[3], UA[3]);                                                \
  }

  for (int i = 0; i < 4; ++i) {
    int nl = w * 4 + i;
    int nU = __builtin_amdgcn_readfirstlane(g0 + nl);
    int eBeg = off[nU], eEnd = off[nU + 1];
    float acc0 = 0.f, acc1 = 0.f;

    uint soA[4], soB[4], uaA[4], uaB[4];
    uint4 evA[4], evB[4];
    int n4 = (eEnd - eBeg) >> 2;
    int e = eBeg;
    if (n4 > 0) {
      SLOAD4(soA, evA, e);
      SLOAD4(soB, evB, e + 4);  // unconditional: CSR padded by 16
      GATHER4(uaA, soA);
      int gg = 0;
      for (; gg + 1 < n4; gg += 2) {
        GATHER4(uaB, soB);
        COMP4(evA, uaA);
        SLOAD4(soA, evA, e + 8);
        GATHER4(uaA, soA);
        COMP4(evB, uaB);
        SLOAD4(soB, evB, e + 12);
        e += 8;
      }
      if (gg < n4) {  // trailing even group lives in A, already gathered
        COMP4(evA, uaA);
        e += 4;
      }
    }
    for (; e < eEnd; ++e) {
      int eU = __builtin_amdgcn_readfirstlane(e);
      uint so = srcoff[eU];
      uint4 ev = *(const uint4*)(ea_h + (size_t)eU * 8);
      uint ua = x2in[so + lane];
      EDGE_COMPUTE(ev, ua);
    }

    uint xp = x2in[(uint)nU * 64u + lane];
    float z0 = __low2float(u2h2(xp)) + acc0;
    float z1 = __high2float(u2h2(xp)) + acc1;
    lzU[nl * 68 + lane] = (uint)f2h_bits(z0) | ((uint)f2h_bits(z1) << 16);
  }
#undef COMP4
#undef GATHER4
#undef SLOAD4
#undef EDGE_COMPUTE
  __syncthreads();

  // ---------------- phase 2: 3-layer MLP (wave = cols [32w, 32w+32)) -------
  f32x4 acc[2];
  f16x8 a[4];
  ushort* lzS = (ushort*)lzU;

  // layer 1: A from lzU (paired k-order matches Wt layer 0)
#pragma unroll
  for (int kk = 0; kk < 4; kk++)
    a[kk] = *(const f16x8*)&lzU[l15 * 68 + kk * 16 + g * 4];
  __syncthreads();  // all A-reads done before z1 stores
#pragma unroll
  for (int c = 0; c < 2; c++) {
    float bv = b1[32 * w + c * 16 + l15];
    acc[c] = (f32x4){bv, bv, bv, bv};
  }
#pragma unroll
  for (int c = 0; c < 2; c++) {
    int col = 32 * w + c * 16 + l15;
#pragma unroll
    for (int kk = 0; kk < 4; kk++) {
      f16x8 bf = *(const f16x8*)(Wt + (size_t)col * 128 + kk * 32 + g * 8);
      acc[c] = __builtin_amdgcn_mfma_f32_16x16x32_f16(a[kk], bf, acc[c], 0, 0, 0);
    }
  }
#pragma unroll
  for (int c = 0; c < 2; c++)
#pragma unroll
    for (int r = 0; r < 4; r++)
      lzS[(4 * g + r) * 136 + 32 * w + c * 16 + l15] =
          f2h_bits(fmaxf(acc[c][r], 0.f));
  __syncthreads();

  // layer 2 (normal k-order)
#pragma unroll
  for (int kk = 0; kk < 4; kk++)
    a[kk] = *(const f16x8*)&lzU[l15 * 68 + kk * 16 + g * 4];
  __syncthreads();
#pragma unroll
  for (int c = 0; c < 2; c++) {
    float bv = b2[32 * w + c * 16 + l15];
    acc[c] = (f32x4){bv, bv, bv, bv};
  }
  {
    const _Float16* W2t = Wt + 16384;
#pragma unroll
    for (int c = 0; c < 2; c++) {
      int col = 32 * w + c * 16 + l15;
#pragma unroll
      for (int kk = 0; kk < 4; kk++) {
        f16x8 bf = *(const f16x8*)(W2t + (size_t)col * 128 + kk * 32 + g * 8);
        acc[c] = __builtin_amdgcn_mfma_f32_16x16x32_f16(a[kk], bf, acc[c], 0, 0, 0);
      }
    }
  }
#pragma unroll
  for (int c = 0; c < 2; c++)
#pragma unroll
    for (int r = 0; r < 4; r++)
      lzS[(4 * g + r) * 136 + 32 * w + c * 16 + l15] =
          f2h_bits(fmaxf(acc[c][r], 0.f));
  __syncthreads();

  // layer 3 (no relu), stage f32 to zf
#pragma unroll
  for (int kk = 0; kk < 4; kk++)
    a[kk] = *(const f16x8*)&lzU[l15 * 68 + kk * 16 + g * 4];
#pragma unroll
  for (int c = 0; c < 2; c++) {
    float bv = b3[32 * w + c * 16 + l15];
    acc[c] = (f32x4){bv, bv, bv, bv};
  }
  {
    const _Float16* W3t = Wt + 32768;
#pragma unroll
    for (int c = 0; c < 2; c++) {
      int col = 32 * w + c * 16 + l15;
#pragma unroll
      for (int kk = 0; kk < 4; kk++) {
        f16x8 bf = *(const f16x8*)(W3t + (size_t)col * 128 + kk * 32 + g * 8);
        acc[c] = __builtin_amdgcn_mfma_f32_16x16x32_f16(a[kk], bf, acc[c], 0, 0, 0);
      }
    }
  }
#pragma unroll
  for (int c = 0; c < 2; c++)
#pragma unroll
    for (int r = 0; r < 4; r++)
      zf[4 * g + r][32 * w + c * 16 + l15] = acc[c][r];
  __syncthreads();

  // ---------------- epilogue: y=z3/std; h+=y; x2out = f16(h/std) -----------
#pragma unroll
  for (int i = 0; i < 4; ++i) {
    int nl = w * 4 + i;
    int n = g0 + nl;
    float z0 = zf[nl][lane], z1 = zf[nl][lane + 64];
    float ss = z0 + z1, s2 = z0 * z0 + z1 * z1;
#pragma unroll
    for (int m = 1; m < 64; m <<= 1) {
      ss += __shfl_xor(ss, m);
      s2 += __shfl_xor(s2, m);
    }
    float inv = 1.0f / sqrtf((s2 - ss * ss * (1.0f / 128.0f)) * (1.0f / 127.0f));
    size_t o = (size_t)n * 128;
    float h0 = h[o + lane] + z0 * inv;
    float h1 = h[o + lane + 64] + z1 * inv;
    float ts = h0 + h1, t2 = h0 * h0 + h1 * h1;
#pragma unroll
    for (int m = 1; m < 64; m <<= 1) {
      ts += __shfl_xor(ts, m);
      t2 += __shfl_xor(t2, m);
    }
    float inv2 = 1.0f / sqrtf((t2 - ts * ts * (1.0f / 128.0f)) * (1.0f / 127.0f));
    h[o + lane] = h0;
    h[o + lane + 64] = h1;
    uint pk = (uint)f2h_bits(h0 * inv2) | ((uint)f2h_bits(h1 * inv2) << 16);
    x2out[(uint)n * 64u + lane] = pk;
  }
}

// -------- output --------
__global__ void k_out(const float* __restrict__ h, const float* __restrict__ oW,
                      const float* __restrict__ ob, float* __restrict__ out) {
  int wid = (blockIdx.x * blockDim.x + threadIdx.x) >> 6;
  int lane = threadIdx.x & 63;
  if (wid >= N_NODES) return;
  int c0 = lane, c1 = lane + 64;
  float w0 = 0.f, w1 = 0.f, bsum = 0.f;
#pragma unroll
  for (int j = 0; j < N_BINARY; j++) {
    float sc = (float)(1 << j);
    w0 += oW[c0 * N_BINARY + j] * sc;
    w1 += oW[c1 * N_BINARY + j] * sc;
    bsum += ob[j] * sc;
  }
  size_t o = (size_t)wid * 128;
  float v = h[o + c0] * w0 + h[o + c1] * w1;
#pragma unroll
  for (int m = 1; m < 64; m <<= 1) v += __shfl_xor(v, m);
  if (lane == 0) out[wid] = v * (1.0f / sqrtf(15.0f)) + bsum;
}

extern "C" void kernel_launch(void* const* d_in, const int* in_sizes, int n_in,
                              void* d_out, int out_size, void* d_ws, size_t ws_size,
                              hipStream_t stream) {
  const float* x = (const float*)d_in[0];
  const int* ei = (const int*)d_in[1];
  const float* eattr = (const float*)d_in[2];
  const float* embW = (const float*)d_in[3];
  const float* embB = (const float*)d_in[4];
  const float* edgeW = (const float*)d_in[5];
  const float* edgeB = (const float*)d_in[6];
  const float* W1 = (const float*)d_in[7];
  const float* b1 = (const float*)d_in[8];
  const float* W2 = (const float*)d_in[9];
  const float* b2 = (const float*)d_in[10];
  const float* W3 = (const float*)d_in[11];
  const float* b3 = (const float*)d_in[12];
  const float* outW = (const float*)d_in[13];
  const float* outB = (const float*)d_in[14];
  float* out = (float*)d_out;

  char* base = (char*)d_ws;
  size_t o = 0;
  auto carve = [&](size_t bytes) {
    size_t start = o;
    o = (start + bytes + 255) & ~(size_t)255;
    return (void*)(base + start);
  };
  int* deg = (int*)carve(N_NODES * sizeof(int));
  int* off = (int*)carve((N_NODES + 1) * sizeof(int));
  int* rnk = (int*)carve(N_EDGES * sizeof(int));
  uint* srcoff = (uint*)carve((N_EDGES + 16) * sizeof(uint));      // +16 pad
  _Float16* ea_h = (_Float16*)carve((size_t)(N_EDGES + 16) * EDGE_DIM * 2);
  uint* x2a = (uint*)carve((size_t)N_NODES * 64 * sizeof(uint));
  uint* x2b = (uint*)carve((size_t)N_NODES * 64 * sizeof(uint));
  float* h = (float*)carve((size_t)N_NODES * N_HIDDEN * sizeof(float));
  _Float16* Wt = (_Float16*)carve((size_t)45 * 16384 * 2);

  hipMemsetAsync(deg, 0, N_NODES * sizeof(int), stream);
  hipMemsetAsync(srcoff + N_EDGES, 0, 16 * sizeof(uint), stream);  // safe pad
  k_embed<<<N_NODES / 4, 256, 0, stream>>>(x, embW, embB, h, x2a);
  k_count<<<(N_EDGES + 255) / 256, 256, 0, stream>>>(ei, deg, rnk);
  k_scan<<<1, 1024, 0, stream>>>(deg, off);
  k_permute<<<(N_EDGES + 255) / 256, 256, 0, stream>>>(ei, eattr, off, rnk, srcoff, ea_h);
  k_prep_w<<<45, 256, 0, stream>>>(W1, W2, W3, Wt);

  for (int b = 0; b < N_BLOCKS; b++) {
    const uint* x2i = (b & 1) ? x2b : x2a;
    uint* x2o = (b & 1) ? x2a : x2b;
    k_block<<<N_NODES / 16, 256, 0, stream>>>(
        off, srcoff, ea_h, x2i, edgeW + (size_t)b * EDGE_DIM * N_HIDDEN,
        edgeB + (size_t)b * N_HIDDEN, Wt + (size_t)b * 3 * 16384,
        b1 + (size_t)b * N_HIDDEN, b2 + (size_t)b * N_HIDDEN,
        b3 + (size_t)b * N_HIDDEN, h, x2o);
  }
  k_out<<<N_NODES / 4, 256, 0, stream>>>(h, outW, outB, out);
}

// Round 9
// 885.870 us; speedup vs baseline: 1.6438x; 1.0805x over previous
//
#include <hip/hip_runtime.h>
#include <hip/hip_bf16.h>
#include <hip/hip_fp16.h>

#define N_NODES 20000
#define N_EDGES 640000
#define N_HIDDEN 128
#define EDGE_DIM 8
#define NODE_DIM 16
#define N_BLOCKS 15
#define N_BINARY 10

typedef __attribute__((ext_vector_type(8))) _Float16 f16x8;
typedef __attribute__((ext_vector_type(4))) float f32x4;
typedef unsigned int uint;
typedef unsigned short ushort;

union U2H {
  uint u;
  __half2 h;
};
static __device__ __forceinline__ __half2 u2h2(uint u) {
  U2H c; c.u = u; return c.h;
}
static __device__ __forceinline__ ushort f2h_bits(float f) {
  union { _Float16 h; ushort u; } c;
  c.h = (_Float16)f;
  return c.u;
}

// ---- embed: h = log(x+1) @ embW + embB ; x2p = packed f16(h/std) -----------
__global__ void k_embed(const float* __restrict__ x, const float* __restrict__ eW,
                        const float* __restrict__ ebias, float* __restrict__ h,
                        uint* __restrict__ x2p) {
  int wid = (blockIdx.x * blockDim.x + threadIdx.x) >> 6;
  int lane = threadIdx.x & 63;
  if (wid >= N_NODES) return;
  float xl[NODE_DIM];
#pragma unroll
  for (int k = 0; k < NODE_DIM; k++) xl[k] = logf(x[wid * NODE_DIM + k] + 1.0f);
  int c0 = lane, c1 = lane + 64;
  float h0 = ebias[c0], h1 = ebias[c1];
#pragma unroll
  for (int k = 0; k < NODE_DIM; k++) {
    h0 += xl[k] * eW[k * N_HIDDEN + c0];
    h1 += xl[k] * eW[k * N_HIDDEN + c1];
  }
  float ss = h0 + h1, s2 = h0 * h0 + h1 * h1;
#pragma unroll
  for (int m = 1; m < 64; m <<= 1) {
    ss += __shfl_xor(ss, m);
    s2 += __shfl_xor(s2, m);
  }
  float var = (s2 - ss * ss * (1.0f / 128.0f)) * (1.0f / 127.0f);
  float inv = 1.0f / sqrtf(var);
  size_t o = (size_t)wid * N_HIDDEN;
  h[o + c0] = h0;
  h[o + c1] = h1;
  uint pk = (uint)f2h_bits(h0 * inv) | ((uint)f2h_bits(h1 * inv) << 16);
  x2p[(size_t)wid * 64 + lane] = pk;
}

// ---------------- CSR build: count also records each edge's rank ------------
__global__ void k_count(const int* __restrict__ ei, int* __restrict__ deg,
                        int* __restrict__ rnk) {
  int e = blockIdx.x * blockDim.x + threadIdx.x;
  if (e < N_EDGES) rnk[e] = atomicAdd(&deg[ei[N_EDGES + e]], 1);
}

__global__ __launch_bounds__(1024) void k_scan(const int* __restrict__ deg,
                                               int* __restrict__ off) {
  __shared__ int wsum[16];
  int t = threadIdx.x;
  int lane = t & 63, w = t >> 6;
  int base = t * 20;
  int loc[20];
  int s = 0;
#pragma unroll
  for (int i = 0; i < 20; i++) {
    int idx = base + i;
    int d = (idx < N_NODES) ? deg[idx] : 0;
    loc[i] = s;
    s += d;
  }
  int incl = s;
#pragma unroll
  for (int m = 1; m < 64; m <<= 1) {
    int o = __shfl_up(incl, m);
    if (lane >= m) incl += o;
  }
  if (lane == 63) wsum[w] = incl;
  __syncthreads();
  if (w == 0) {
    int xv = (lane < 16) ? wsum[lane] : 0;
#pragma unroll
    for (int m = 1; m < 16; m <<= 1) {
      int o = __shfl_up(xv, m);
      if (lane >= m) xv += o;
    }
    if (lane < 16) wsum[lane] = xv;
  }
  __syncthreads();
  int woff = (w == 0) ? 0 : wsum[w - 1];
  int texcl = woff + incl - s;
#pragma unroll
  for (int i = 0; i < 20; i++) {
    int idx = base + i;
    if (idx < N_NODES) off[idx] = texcl + loc[i];
  }
  if (t == 0) off[N_NODES] = wsum[15];
}

// permute edges dst-sorted (atomic-free: pos = off[dst] + rnk[e])
__global__ void k_permute(const int* __restrict__ ei, const float* __restrict__ eattr,
                          const int* __restrict__ off, const int* __restrict__ rnk,
                          uint* __restrict__ srcoff, _Float16* __restrict__ ea_h) {
  int e = blockIdx.x * blockDim.x + threadIdx.x;
  if (e >= N_EDGES) return;
  int d = ei[N_EDGES + e];
  int pos = off[d] + rnk[e];
  srcoff[pos] = (uint)ei[e] * 64u;
  const float4* ap = (const float4*)(eattr + (size_t)e * 8);
  float4 a0 = ap[0], a1 = ap[1];
  f16x8 r;
  r[0] = (_Float16)logf(a0.x + 1.0f);
  r[1] = (_Float16)logf(a0.y + 1.0f);
  r[2] = (_Float16)logf(a0.z + 1.0f);
  r[3] = (_Float16)logf(a0.w + 1.0f);
  r[4] = (_Float16)logf(a1.x + 1.0f);
  r[5] = (_Float16)logf(a1.y + 1.0f);
  r[6] = (_Float16)logf(a1.z + 1.0f);
  r[7] = (_Float16)logf(a1.w + 1.0f);
  *(f16x8*)(ea_h + (size_t)pos * 8) = r;
}

// ---- weight transpose+f16. layer 0 gets paired k-order to match packed z ---
__global__ void k_prep_w(const float* __restrict__ W1, const float* __restrict__ W2,
                         const float* __restrict__ W3, _Float16* __restrict__ Wt) {
  __shared__ _Float16 t[128][130];
  int m = blockIdx.x;  // 0..44 = blk*3+layer
  int blk = m / 3, layer = m % 3;
  const float* src = (layer == 0 ? W1 : layer == 1 ? W2 : W3) + (size_t)blk * 16384;
  int tid = threadIdx.x;
  for (int idx = tid; idx < 16384; idx += 256) {
    int k = idx >> 7, n = idx & 127;
    t[k][n] = (_Float16)src[idx];
  }
  __syncthreads();
  _Float16* dst = Wt + (size_t)m * 16384;
  if (layer == 0) {
    for (int idx = tid; idx < 16384; idx += 256) {
      int n = idx >> 7, p = idx & 127;
      int k = (p >> 1) + 64 * (p & 1);  // paired k-order
      dst[idx] = t[k][n];
    }
  } else {
    for (int idx = tid; idx < 16384; idx += 256) {
      int n = idx >> 7, k = idx & 127;
      dst[idx] = t[k][n];
    }
  }
}

// ======== FUSED per-GNN-block kernel: msg + 3-layer MLP + norm ==============
// 1250 blocks x 512 thr (8 waves); 16 nodes/block; z lives in LDS only.
__global__ __launch_bounds__(512) void k_block(
    const int* __restrict__ off, const uint* __restrict__ srcoff,
    const _Float16* __restrict__ ea_h, const uint* __restrict__ x2in,
    const float* __restrict__ eW, const float* __restrict__ ebias,
    const _Float16* __restrict__ Wt, const float* __restrict__ b1,
    const float* __restrict__ b2, const float* __restrict__ b3,
    float* __restrict__ h, uint* __restrict__ x2out) {
  __shared__ __align__(16) uint lzU[16 * 68];  // rows pitch 68 uints (272B)
  __shared__ float zf[16][132];
  int tid = threadIdx.x;
  int w = tid >> 6, lane = tid & 63;
  int l15 = lane & 15, g = lane >> 4;
  int g0 = blockIdx.x * 16;  // 1250*16 = 20000 exact

  // ---------------- phase 1: message + aggregate (wave owns 2 nodes) --------
  __half2 w0pk[4], w1pk[4];
#pragma unroll
  for (int j = 0; j < 4; j++) {
    w0pk[j] = __floats2half2_rn(eW[(2 * j) * N_HIDDEN + lane],
                                eW[(2 * j + 1) * N_HIDDEN + lane]);
    w1pk[j] = __floats2half2_rn(eW[(2 * j) * N_HIDDEN + lane + 64],
                                eW[(2 * j + 1) * N_HIDDEN + lane + 64]);
  }
  __half2 bb01 = __floats2half2_rn(ebias[lane], ebias[lane + 64]);

#define EDGE_COMPUTE(EV, UA)                                                   \
  {                                                                            \
    __half2 pA = __hmul2(u2h2((EV).x), w0pk[0]);                               \
    pA = __hfma2(u2h2((EV).y), w0pk[1], pA);                                   \
    pA = __hfma2(u2h2((EV).z), w0pk[2], pA);                                   \
    pA = __hfma2(u2h2((EV).w), w0pk[3], pA);                                   \
    __half2 pB = __hmul2(u2h2((EV).x), w1pk[0]);                               \
    pB = __hfma2(u2h2((EV).y), w1pk[1], pB);                                   \
    pB = __hfma2(u2h2((EV).z), w1pk[2], pB);                                   \
    pB = __hfma2(u2h2((EV).w), w1pk[3], pB);                                   \
    __half v0 = __hadd(__low2half(pA), __high2half(pA));                       \
    __half v1 = __hadd(__low2half(pB), __high2half(pB));                       \
    __half2 mm = __hadd2(__halves2half2(v0, v1), __hadd2(u2h2(UA), bb01));     \
    acc0 += fmaxf(__low2float(mm), 0.f);                                       \
    acc1 += fmaxf(__high2float(mm), 0.f);                                      \
  }
#define SLOAD4(SO, EV, EE)                                                     \
  {                                                                            \
    int eU_ = __builtin_amdgcn_readfirstlane(EE);                              \
    SO[0] = srcoff[eU_];                                                       \
    SO[1] = srcoff[eU_ + 1];                                                   \
    SO[2] = srcoff[eU_ + 2];                                                   \
    SO[3] = srcoff[eU_ + 3];                                                   \
    const uint4* ep_ = (const uint4*)(ea_h + (size_t)eU_ * 8);                 \
    EV[0] = ep_[0];                                                            \
    EV[1] = ep_[1];                                                            \
    EV[2] = ep_[2];                                                            \
    EV[3] = ep_[3];                                                            \
  }
#define GATHER4(UA, SO)                                                        \
  {                                                                            \
    UA[0] = x2in[SO[0] + lane];                                                \
    UA[1] = x2in[SO[1] + lane];                                                \
    UA[2] = x2in[SO[2] + lane];                                                \
    UA[3] = x2in[SO[3] + lane];                                                \
  }
#define COMP4(EV, UA)                                                          \
  {                                                                            \
    EDGE_COMPUTE(EV[0], UA[0]);                                                \
    EDGE_COMPUTE(EV[1], UA[1]);                                                \
    EDGE_COMPUTE(EV[2], UA[2]);                                                \
    EDGE_COMPUTE(EV[3], UA[3]);                                                \
  }

  for (int i = 0; i < 2; ++i) {
    int nl = w * 2 + i;
    int nU = __builtin_amdgcn_readfirstlane(g0 + nl);
    int eBeg = off[nU], eEnd = off[nU + 1];
    float acc0 = 0.f, acc1 = 0.f;

    uint soA[4], soB[4], uaA[4], uaB[4];
    uint4 evA[4], evB[4];
    int n4 = (eEnd - eBeg) >> 2;
    int e = eBeg;
    if (n4 > 0) {
      SLOAD4(soA, evA, e);
      SLOAD4(soB, evB, e + 4);  // unconditional: CSR padded by 16
      GATHER4(uaA, soA);
      int gg = 0;
      for (; gg + 1 < n4; gg += 2) {
        GATHER4(uaB, soB);
        COMP4(evA, uaA);
        SLOAD4(soA, evA, e + 8);
        GATHER4(uaA, soA);
        COMP4(evB, uaB);
        SLOAD4(soB, evB, e + 12);
        e += 8;
      }
      if (gg < n4) {  // trailing even group lives in A, already gathered
        COMP4(evA, uaA);
        e += 4;
      }
    }
    for (; e < eEnd; ++e) {
      int eU = __builtin_amdgcn_readfirstlane(e);
      uint so = srcoff[eU];
      uint4 ev = *(const uint4*)(ea_h + (size_t)eU * 8);
      uint ua = x2in[so + lane];
      EDGE_COMPUTE(ev, ua);
    }

    uint xp = x2in[(uint)nU * 64u + lane];
    float z0 = __low2float(u2h2(xp)) + acc0;
    float z1 = __high2float(u2h2(xp)) + acc1;
    lzU[nl * 68 + lane] = (uint)f2h_bits(z0) | ((uint)f2h_bits(z1) << 16);
  }
#undef COMP4
#undef GATHER4
#undef SLOAD4
#undef EDGE_COMPUTE
  __syncthreads();

  // ------- phase 2: 3-layer MLP; wave owns cols [16w, 16w+16) --------------
  f32x4 acc;
  f16x8 a[4];
  ushort* lzS = (ushort*)lzU;
  int col = 16 * w + l15;

  // layer 1: A from lzU (paired k-order matches Wt layer 0)
#pragma unroll
  for (int kk = 0; kk < 4; kk++)
    a[kk] = *(const f16x8*)&lzU[l15 * 68 + kk * 16 + g * 4];
  __syncthreads();  // all A-reads done before z1 stores
  {
    float bv = b1[col];
    acc = (f32x4){bv, bv, bv, bv};
#pragma unroll
    for (int kk = 0; kk < 4; kk++) {
      f16x8 bf = *(const f16x8*)(Wt + (size_t)col * 128 + kk * 32 + g * 8);
      acc = __builtin_amdgcn_mfma_f32_16x16x32_f16(a[kk], bf, acc, 0, 0, 0);
    }
  }
#pragma unroll
  for (int r = 0; r < 4; r++)
    lzS[(4 * g + r) * 136 + col] = f2h_bits(fmaxf(acc[r], 0.f));
  __syncthreads();

  // layer 2 (normal k-order)
#pragma unroll
  for (int kk = 0; kk < 4; kk++)
    a[kk] = *(const f16x8*)&lzU[l15 * 68 + kk * 16 + g * 4];
  __syncthreads();
  {
    const _Float16* W2t = Wt + 16384;
    float bv = b2[col];
    acc = (f32x4){bv, bv, bv, bv};
#pragma unroll
    for (int kk = 0; kk < 4; kk++) {
      f16x8 bf = *(const f16x8*)(W2t + (size_t)col * 128 + kk * 32 + g * 8);
      acc = __builtin_amdgcn_mfma_f32_16x16x32_f16(a[kk], bf, acc, 0, 0, 0);
    }
  }
#pragma unroll
  for (int r = 0; r < 4; r++)
    lzS[(4 * g + r) * 136 + col] = f2h_bits(fmaxf(acc[r], 0.f));
  __syncthreads();

  // layer 3 (no relu), stage f32 to zf
#pragma unroll
  for (int kk = 0; kk < 4; kk++)
    a[kk] = *(const f16x8*)&lzU[l15 * 68 + kk * 16 + g * 4];
  {
    const _Float16* W3t = Wt + 32768;
    float bv = b3[col];
    acc = (f32x4){bv, bv, bv, bv};
#pragma unroll
    for (int kk = 0; kk < 4; kk++) {
      f16x8 bf = *(const f16x8*)(W3t + (size_t)col * 128 + kk * 32 + g * 8);
      acc = __builtin_amdgcn_mfma_f32_16x16x32_f16(a[kk], bf, acc, 0, 0, 0);
    }
  }
#pragma unroll
  for (int r = 0; r < 4; r++) zf[4 * g + r][col] = acc[r];
  __syncthreads();

  // ---------------- epilogue: y=z3/std; h+=y; x2out = f16(h/std) -----------
#pragma unroll
  for (int i = 0; i < 2; ++i) {
    int nl = w * 2 + i;
    int n = g0 + nl;
    float z0 = zf[nl][lane], z1 = zf[nl][lane + 64];
    float ss = z0 + z1, s2 = z0 * z0 + z1 * z1;
#pragma unroll
    for (int m = 1; m < 64; m <<= 1) {
      ss += __shfl_xor(ss, m);
      s2 += __shfl_xor(s2, m);
    }
    float inv = 1.0f / sqrtf((s2 - ss * ss * (1.0f / 128.0f)) * (1.0f / 127.0f));
    size_t o = (size_t)n * 128;
    float h0 = h[o + lane] + z0 * inv;
    float h1 = h[o + lane + 64] + z1 * inv;
    float ts = h0 + h1, t2 = h0 * h0 + h1 * h1;
#pragma unroll
    for (int m = 1; m < 64; m <<= 1) {
      ts += __shfl_xor(ts, m);
      t2 += __shfl_xor(t2, m);
    }
    float inv2 = 1.0f / sqrtf((t2 - ts * ts * (1.0f / 128.0f)) * (1.0f / 127.0f));
    h[o + lane] = h0;
    h[o + lane + 64] = h1;
    uint pk = (uint)f2h_bits(h0 * inv2) | ((uint)f2h_bits(h1 * inv2) << 16);
    x2out[(uint)n * 64u + lane] = pk;
  }
}

// -------- output --------
__global__ void k_out(const float* __restrict__ h, const float* __restrict__ oW,
                      const float* __restrict__ ob, float* __restrict__ out) {
  int wid = (blockIdx.x * blockDim.x + threadIdx.x) >> 6;
  int lane = threadIdx.x & 63;
  if (wid >= N_NODES) return;
  int c0 = lane, c1 = lane + 64;
  float w0 = 0.f, w1 = 0.f, bsum = 0.f;
#pragma unroll
  for (int j = 0; j < N_BINARY; j++) {
    float sc = (float)(1 << j);
    w0 += oW[c0 * N_BINARY + j] * sc;
    w1 += oW[c1 * N_BINARY + j] * sc;
    bsum += ob[j] * sc;
  }
  size_t o = (size_t)wid * 128;
  float v = h[o + c0] * w0 + h[o + c1] * w1;
#pragma unroll
  for (int m = 1; m < 64; m <<= 1) v += __shfl_xor(v, m);
  if (lane == 0) out[wid] = v * (1.0f / sqrtf(15.0f)) + bsum;
}

extern "C" void kernel_launch(void* const* d_in, const int* in_sizes, int n_in,
                              void* d_out, int out_size, void* d_ws, size_t ws_size,
                              hipStream_t stream) {
  const float* x = (const float*)d_in[0];
  const int* ei = (const int*)d_in[1];
  const float* eattr = (const float*)d_in[2];
  const float* embW = (const float*)d_in[3];
  const float* embB = (const float*)d_in[4];
  const float* edgeW = (const float*)d_in[5];
  const float* edgeB = (const float*)d_in[6];
  const float* W1 = (const float*)d_in[7];
  const float* b1 = (const float*)d_in[8];
  const float* W2 = (const float*)d_in[9];
  const float* b2 = (const float*)d_in[10];
  const float* W3 = (const float*)d_in[11];
  const float* b3 = (const float*)d_in[12];
  const float* outW = (const float*)d_in[13];
  const float* outB = (const float*)d_in[14];
  float* out = (float*)d_out;

  char* base = (char*)d_ws;
  size_t o = 0;
  auto carve = [&](size_t bytes) {
    size_t start = o;
    o = (start + bytes + 255) & ~(size_t)255;
    return (void*)(base + start);
  };
  int* deg = (int*)carve(N_NODES * sizeof(int));
  int* off = (int*)carve((N_NODES + 1) * sizeof(int));
  int* rnk = (int*)carve(N_EDGES * sizeof(int));
  uint* srcoff = (uint*)carve((N_EDGES + 16) * sizeof(uint));      // +16 pad
  _Float16* ea_h = (_Float16*)carve((size_t)(N_EDGES + 16) * EDGE_DIM * 2);
  uint* x2a = (uint*)carve((size_t)N_NODES * 64 * sizeof(uint));
  uint* x2b = (uint*)carve((size_t)N_NODES * 64 * sizeof(uint));
  float* h = (float*)carve((size_t)N_NODES * N_HIDDEN * sizeof(float));
  _Float16* Wt = (_Float16*)carve((size_t)45 * 16384 * 2);

  hipMemsetAsync(deg, 0, N_NODES * sizeof(int), stream);
  hipMemsetAsync(srcoff + N_EDGES, 0, 16 * sizeof(uint), stream);  // safe pad
  k_embed<<<N_NODES / 4, 256, 0, stream>>>(x, embW, embB, h, x2a);
  k_count<<<(N_EDGES + 255) / 256, 256, 0, stream>>>(ei, deg, rnk);
  k_scan<<<1, 1024, 0, stream>>>(deg, off);
  k_permute<<<(N_EDGES + 255) / 256, 256, 0, stream>>>(ei, eattr, off, rnk, srcoff, ea_h);
  k_prep_w<<<45, 256, 0, stream>>>(W1, W2, W3, Wt);

  for (int b = 0; b < N_BLOCKS; b++) {
    const uint* x2i = (b & 1) ? x2b : x2a;
    uint* x2o = (b & 1) ? x2a : x2b;
    k_block<<<N_NODES / 16, 512, 0, stream>>>(
        off, srcoff, ea_h, x2i, edgeW + (size_t)b * EDGE_DIM * N_HIDDEN,
        edgeB + (size_t)b * N_HIDDEN, Wt + (size_t)b * 3 * 16384,
        b1 + (size_t)b * N_HIDDEN, b2 + (size_t)b * N_HIDDEN,
        b3 + (size_t)b * N_HIDDEN, h, x2o);
  }
  k_out<<<N_NODES / 4, 256, 0, stream>>>(h, outW, outB, out);
}